// Round 9
// baseline (3350.971 us; speedup 1.0000x reference)
//
#include <hip/hip_runtime.h>

#define TT 2048

typedef _Float16 f16;
typedef _Float16 f16x2 __attribute__((ext_vector_type(2)));
typedef _Float16 f16x8 __attribute__((ext_vector_type(8)));
typedef float f32x4 __attribute__((ext_vector_type(4)));
typedef unsigned int u32;

static __device__ __forceinline__ u32 packh2(float a, float b) {
  f16x2 v; v[0] = (f16)a; v[1] = (f16)b;
  return __builtin_bit_cast(u32, v);
}
static __device__ __forceinline__ uint4 pack8(float4 a, float4 b) {
  uint4 r;
  r.x = packh2(a.x, a.y); r.y = packh2(a.z, a.w);
  r.z = packh2(b.x, b.y); r.w = packh2(b.z, b.w);
  return r;
}
static __device__ __forceinline__ float sigm(float x) {
  return 1.f / (1.f + __expf(-x));
}
static __device__ __forceinline__ float tanh_(float x) {
  x = fminf(15.f, fmaxf(-15.f, x));
  const float e = __expf(2.f * x);
  return (e - 1.f) / (e + 1.f);
}
// B-fragment for mfma_f32_16x16x32_f16 from row-major W[rows][ld] (f32):
// lane holds B[k][n]=W[G+(l&15)][kbase + i], i=0..7.
static __device__ __forceinline__ f16x8 ldwfrag(const float* __restrict__ W,
                                                int row, int ld, int kbase) {
  const float* p = W + row * ld + kbase;
  const float4 a = *(const float4*)p;
  const float4 b = *(const float4*)(p + 4);
  f16x8 r;
  r[0]=(f16)a.x; r[1]=(f16)a.y; r[2]=(f16)a.z; r[3]=(f16)a.w;
  r[4]=(f16)b.x; r[5]=(f16)b.y; r[6]=(f16)b.z; r[7]=(f16)b.w;
  return r;
}
static __device__ __forceinline__ f32x4 MF(f16x8 a, f16x8 b, f32x4 c) {
  return __builtin_amdgcn_mfma_f32_16x16x32_f16(a, b, c, 0, 0, 0);
}

// MFMA persistent LSTM, flag-synced (NO __syncthreads in the 2048-step loop).
// One block = 16 batch rows, 7 waves on one CU:
//   waves 0-3 (L1): own 16 units each; x-MFMAs issued BEFORE the h-poll.
//   waves 4-5 (L2): one step behind, consume h1[t] + h2[t-1].
//   wave 6: x staging, batches of 8 steps, free-runs ahead via a 16-slot ring.
// Sync = volatile LDS step-counters (producer: data ds_writes ->
// s_waitcnt lgkmcnt(0) -> flag write; consumer: spin on flag, then read).
// All waves share one CU's LDS, so no cross-XCD coherence concerns; rings are
// deep enough (h:4, x:16) that back-pressure polls almost never spin.
__launch_bounds__(448, 1)
__global__ void lstm2_flag_kernel(const float* __restrict__ x1,
                                  const float* __restrict__ x2,
                                  const float* __restrict__ Wih1,
                                  const float* __restrict__ Whh1,
                                  const float* __restrict__ bih1,
                                  const float* __restrict__ bhh1,
                                  const float* __restrict__ Wih2,
                                  const float* __restrict__ Whh2,
                                  const float* __restrict__ bih2,
                                  const float* __restrict__ bhh2,
                                  float* __restrict__ out)
{
  __shared__ __align__(16) u32 s_ring[16][512];   // x ring, slot = t & 15
  __shared__ __align__(16) f16 s_h1[4][16][72];   // h1 ring, slot = t & 3
  __shared__ __align__(16) f16 s_h2[4][16][40];   // h2 ring, slot = t & 3
  __shared__ int s_fh1[4];   // L1 wave w: steps completed
  __shared__ int s_fh2[2];   // L2 wave w2: steps completed
  __shared__ int s_fx;       // x steps staged

  const int tid = threadIdx.x;
  const int l = tid & 63;
  const int wid = tid >> 6;        // 0-3 L1, 4-5 L2, 6 x-stage
  const int ln = l & 15;
  const int lg = l >> 4;           // k-group 0..3
  const int bid = blockIdx.x;      // 32 blocks
  const int which = bid >> 4;
  const int rowbase = (bid & 15) * 16;

  // zero h1[-1], h2[-1] (slot 3) + flags
  for (int idx = tid; idx < 16 * 72; idx += 448) ((f16*)s_h1[3])[idx] = (f16)0.f;
  for (int idx = tid; idx < 16 * 40; idx += 448) ((f16*)s_h2[3])[idx] = (f16)0.f;
  if (tid < 4) s_fh1[tid] = 0;
  if (tid < 2) s_fh2[tid] = 0;
  if (tid == 0) s_fx = 8;

  // ---- per-wave weight fragments (validated in R8) ----
  f16x8 wx[4][2];
  f16x8 wh[4][2];
  float bs[4] = {0.f, 0.f, 0.f, 0.f};
  #pragma unroll
  for (int q = 0; q < 4; ++q) { wx[q][0] = wx[q][1] = wh[q][0] = wh[q][1] = (f16x8)(f16)0.f; }

  if (wid < 4) {
    #pragma unroll
    for (int q = 0; q < 4; ++q) {
      const int g = 64 * q + 16 * wid + ln;
      #pragma unroll
      for (int c = 0; c < 2; ++c) {
        wx[q][c] = ldwfrag(Wih1, g, 64, 32 * c + lg * 8);
        wh[q][c] = ldwfrag(Whh1, g, 64, 32 * c + lg * 8);
      }
      bs[q] = bih1[g] + bhh1[g];
    }
  } else if (wid < 6) {
    const int w2 = wid - 4;
    #pragma unroll
    for (int q = 0; q < 4; ++q) {
      const int g = 32 * q + 16 * w2 + ln;
      #pragma unroll
      for (int c = 0; c < 2; ++c) wx[q][c] = ldwfrag(Wih2, g, 64, 32 * c + lg * 8);
      wh[q][0] = ldwfrag(Whh2, g, 32, lg * 8);
      bs[q] = bih2[g] + bhh2[g];
    }
  }

  const int uu = 16 * ((wid < 4) ? wid : (wid - 4)) + ln;
  float cc[4] = {0.f, 0.f, 0.f, 0.f};

  const float* __restrict__ xrow =
      (which ? x2 : x1) + (size_t)(rowbase + ln) * (TT * 64);

  // ---- stager prologue: steps 0..7 into ring slots 0..7 ----
  if (wid == 6) {
    #pragma unroll 1
    for (int p = 0; p < 8; ++p) {
      const float* ps = xrow + p * 64;
      const float4 a0 = *(const float4*)(ps + lg * 8);
      const float4 a1 = *(const float4*)(ps + lg * 8 + 4);
      const float4 b0 = *(const float4*)(ps + 32 + lg * 8);
      const float4 b1 = *(const float4*)(ps + 32 + lg * 8 + 4);
      *(uint4*)&s_ring[p][lg * 64 + ln * 4] = pack8(a0, a1);
      *(uint4*)&s_ring[p][256 + lg * 64 + ln * 4] = pack8(b0, b1);
    }
  }
  __syncthreads();   // the ONLY barrier

  volatile int* fh1 = (volatile int*)s_fh1;
  volatile int* fh2 = (volatile int*)s_fh2;
  volatile int* fx  = (volatile int*)&s_fx;

  if (wid < 4) {
    // ================= layer-1 serial waves =================
    #pragma unroll 1
    for (int i = 0; i < TT; ++i) {
      while (*fx < i + 1) { }
      const u32* rs = s_ring[i & 15];
      const f16x8 xa0 = *(const f16x8*)&rs[lg * 64 + ln * 4];
      const f16x8 xa1 = *(const f16x8*)&rs[256 + lg * 64 + ln * 4];
      f32x4 a0 = {bs[0], bs[0], bs[0], bs[0]};
      f32x4 a1 = {bs[1], bs[1], bs[1], bs[1]};
      f32x4 a2 = {bs[2], bs[2], bs[2], bs[2]};
      f32x4 a3 = {bs[3], bs[3], bs[3], bs[3]};
      a0 = MF(xa0, wx[0][0], a0); a1 = MF(xa0, wx[1][0], a1);
      a2 = MF(xa0, wx[2][0], a2); a3 = MF(xa0, wx[3][0], a3);
      a0 = MF(xa1, wx[0][1], a0); a1 = MF(xa1, wx[1][1], a1);
      a2 = MF(xa1, wx[2][1], a2); a3 = MF(xa1, wx[3][1], a3);
      // wait for all four peers to have finished step i-1
      while (fh1[0] < i || fh1[1] < i || fh1[2] < i || fh1[3] < i) { }
      const f16* hb = &s_h1[(i - 1) & 3][ln][lg * 8];
      const f16x8 ha0 = *(const f16x8*)hb;
      const f16x8 ha1 = *(const f16x8*)(hb + 32);
      a0 = MF(ha0, wh[0][0], a0); a1 = MF(ha0, wh[1][0], a1);
      a2 = MF(ha0, wh[2][0], a2); a3 = MF(ha0, wh[3][0], a3);
      a0 = MF(ha1, wh[0][1], a0); a1 = MF(ha1, wh[1][1], a1);
      a2 = MF(ha1, wh[2][1], a2); a3 = MF(ha1, wh[3][1], a3);
      // back-pressure: slot i&3 held h1[i-4]; L2 must be past step i-4
      while (fh2[0] < i - 3 || fh2[1] < i - 3) { }
      #pragma unroll
      for (int r2 = 0; r2 < 4; ++r2) {
        const float gi = sigm(a0[r2]), gf = sigm(a1[r2]);
        const float gg = tanh_(a2[r2]), go = sigm(a3[r2]);
        cc[r2] = gf * cc[r2] + gi * gg;
        const float hv = go * tanh_(cc[r2]);
        s_h1[i & 3][lg * 4 + r2][uu] = (f16)hv;
      }
      asm volatile("s_waitcnt lgkmcnt(0)" ::: "memory");
      if (l == 0) fh1[wid] = i + 1;
    }
  } else if (wid < 6) {
    // ================= layer-2 waves (skewed) =================
    const int w2 = wid - 4;
    #pragma unroll 1
    for (int t = 0; t < TT; ++t) {
      while (fh1[0] < t + 1 || fh1[1] < t + 1 ||
             fh1[2] < t + 1 || fh1[3] < t + 1) { }
      while (fh2[0] < t || fh2[1] < t) { }
      const f16* hb = &s_h1[t & 3][ln][lg * 8];
      const f16x8 ha0 = *(const f16x8*)hb;
      const f16x8 ha1 = *(const f16x8*)(hb + 32);
      const f16x8 g0 = *(const f16x8*)&s_h2[(t - 1) & 3][ln][lg * 8];
      f32x4 b0 = {bs[0], bs[0], bs[0], bs[0]};
      f32x4 b1 = {bs[1], bs[1], bs[1], bs[1]};
      f32x4 b2 = {bs[2], bs[2], bs[2], bs[2]};
      f32x4 b3 = {bs[3], bs[3], bs[3], bs[3]};
      b0 = MF(ha0, wx[0][0], b0); b1 = MF(ha0, wx[1][0], b1);
      b2 = MF(ha0, wx[2][0], b2); b3 = MF(ha0, wx[3][0], b3);
      b0 = MF(ha1, wx[0][1], b0); b1 = MF(ha1, wx[1][1], b1);
      b2 = MF(ha1, wx[2][1], b2); b3 = MF(ha1, wx[3][1], b3);
      b0 = MF(g0, wh[0][0], b0);  b1 = MF(g0, wh[1][0], b1);
      b2 = MF(g0, wh[2][0], b2);  b3 = MF(g0, wh[3][0], b3);
      #pragma unroll
      for (int r2 = 0; r2 < 4; ++r2) {
        const float gi = sigm(b0[r2]), gf = sigm(b1[r2]);
        const float gg = tanh_(b2[r2]), go = sigm(b3[r2]);
        cc[r2] = gf * cc[r2] + gi * gg;
        const float hv = go * tanh_(cc[r2]);
        s_h2[t & 3][lg * 4 + r2][uu] = (f16)hv;
        if (t == TT - 1)
          out[which * 8192 + (rowbase + lg * 4 + r2) * 32 + uu] = hv;
      }
      asm volatile("s_waitcnt lgkmcnt(0)" ::: "memory");
      if (l == 0) fh2[w2] = t + 1;
    }
  } else {
    // ================= x stager =================
    #pragma unroll 1
    for (int s = 8; s < TT; s += 8) {
      // ring slots (s..s+7)&15 held steps s-16..s-9; L1 must be past s-9
      while (fh1[0] < s - 8 || fh1[1] < s - 8 ||
             fh1[2] < s - 8 || fh1[3] < s - 8) { }
      #pragma unroll
      for (int p = 0; p < 8; ++p) {
        const float* ps = xrow + (s + p) * 64;
        const float4 a0 = *(const float4*)(ps + lg * 8);
        const float4 a1 = *(const float4*)(ps + lg * 8 + 4);
        const float4 b0 = *(const float4*)(ps + 32 + lg * 8);
        const float4 b1 = *(const float4*)(ps + 32 + lg * 8 + 4);
        u32* rd = s_ring[(s + p) & 15];
        *(uint4*)&rd[lg * 64 + ln * 4] = pack8(a0, a1);
        *(uint4*)&rd[256 + lg * 64 + ln * 4] = pack8(b0, b1);
      }
      asm volatile("s_waitcnt lgkmcnt(0)" ::: "memory");
      if (l == 0) *fx = s + 8;
    }
  }
}

extern "C" void kernel_launch(void* const* d_in, const int* in_sizes, int n_in,
                              void* d_out, int out_size, void* d_ws, size_t ws_size,
                              hipStream_t stream) {
  const float* x1   = (const float*)d_in[0];
  const float* x2   = (const float*)d_in[1];
  const float* Wih1 = (const float*)d_in[2];
  const float* Whh1 = (const float*)d_in[3];
  const float* bih1 = (const float*)d_in[4];
  const float* bhh1 = (const float*)d_in[5];
  const float* Wih2 = (const float*)d_in[6];
  const float* Whh2 = (const float*)d_in[7];
  const float* bih2 = (const float*)d_in[8];
  const float* bhh2 = (const float*)d_in[9];
  float* out = (float*)d_out;

  lstm2_flag_kernel<<<dim3(32), dim3(448), 0, stream>>>(
      x1, x2, Wih1, Whh1, bih1, bhh1, Wih2, Whh2, bih2, bhh2, out);
}